// Round 3
// baseline (90.843 us; speedup 1.0000x reference)
//
#include <hip/hip_runtime.h>
#include <hip/hip_bf16.h>

typedef float f2 __attribute__((ext_vector_type(2)));
typedef float f4 __attribute__((ext_vector_type(4)));

constexpr int Hh = 224, Ww = 224, Bb = 8, Kc = 4, RAD = 5;

// 128 threads = 32x4; each thread computes T=4 vertical centers -> 32x16 tile
constexpr int TX = 32;
constexpr int T  = 4;
constexpr int TILEH = 16;             // 4 thread-rows * T
constexpr int SW = TX + 2 * RAD;      // 42
constexpr int SH = TILEH + 2 * RAD;   // 26
constexpr int SSTR = SW + 1;          // 43 (odd -> conflict-free; col 42 = pad column)
constexpr int GXD = Ww / TX;          // 7
constexpr int GYD = Hh / TILEH;       // 14
constexpr int PB = GXD * GYD;         // 98 blocks per batch image

constexpr float LOG2E = 1.44269504f;
constexpr float KI  = -0.01f * LOG2E;     // intensity coeff (exp2 domain)
constexpr float DSC = -0.0625f * LOG2E;   // distance coeff  (exp2 domain)

static __device__ inline f4 splat4(float x) { return (f4){x, x, x, x}; }

__global__ __launch_bounds__(128) void ncut_main(const float* __restrict__ images,
                                                 const float* __restrict__ labels,
                                                 float* __restrict__ acc) {
    __shared__ float simg[SH * SSTR];
    __shared__ f4    slab[SH * SSTR];
    __shared__ float red[2][8];

    const int b   = blockIdx.z;
    const int x0  = blockIdx.x * TX;
    const int y0  = blockIdx.y * TILEH;
    const int tid = threadIdx.x;

    const float* imgb = images + (size_t)b * (Hh * Ww);
    const float* labb = labels + (size_t)b * (Kc * Hh * Ww);

    // Stage tile + halo (incl. stride-pad column as OOB).
    // OOB: img = 1e19 -> weight underflows to exactly 0; labels = 0.
    for (int idx = tid; idx < SH * SSTR; idx += 128) {
        const int lx = idx % SSTR, ly = idx / SSTR;
        const int gx = x0 - RAD + lx, gy = y0 - RAD + ly;
        float iv = 1e19f;
        f4 lv = (f4){0.f, 0.f, 0.f, 0.f};
        if (lx < SW && gx >= 0 && gx < Ww && gy >= 0 && gy < Hh) {
            const int g = gy * Ww + gx;
            iv = imgb[g] * 255.0f;
            lv = (f4){labb[g], labb[Hh * Ww + g], labb[2 * Hh * Ww + g], labb[3 * Hh * Ww + g]};
        }
        simg[idx] = iv;
        slab[idx] = lv;
    }
    __syncthreads();

    const int tx   = tid & 31;
    const int trow = tid >> 5;        // 0..3
    const int r0   = trow * T;        // top LDS row of this thread's 14-row window

    float ci[T];
#pragma unroll
    for (int c = 0; c < T; ++c) ci[c] = simg[(r0 + c + RAD) * SSTR + tx + RAD];

    f4 num[T];
    f2 den[T];
#pragma unroll
    for (int c = 0; c < T; ++c) { num[c] = splat4(0.f); den[c] = (f2){0.f, 0.f}; }

    // Rolled row loop (small body, no rodata tables): row dr serves center c iff
    // |dr - c - 5| <= 5; inactive combos get dyw = 0 (branch-free).
    for (int dr = 0; dr < T + 10; ++dr) {
        const int rowoff = (r0 + dr) * SSTR + tx;
        float dyw[T];
#pragma unroll
        for (int c = 0; c < T; ++c) {
            const int   di = dr - c - RAD;
            const float fd = (float)(di * di);
            const float e  = __builtin_amdgcn_exp2f(fd * DSC);
            dyw[c] = (fd <= 25.f) ? e : 0.f;
        }
#pragma unroll
        for (int i = 0; i < 6; ++i) {
            const f2 v  = (f2){simg[rowoff + 2 * i], simg[rowoff + 2 * i + 1]};
            const f4 p0 = slab[rowoff + 2 * i];
            const f4 p1 = slab[rowoff + 2 * i + 1];
            // dx^2 terms are compile-time immediates (i fully unrolled);
            // column offset 11 (i=5,.y) is the pairing pad: -1e38 -> weight 0.
            const float dxa = (float)((2 * i - 5) * (2 * i - 5)) * DSC;
            const float dxb = (2 * i + 1 < 11)
                                  ? (float)((2 * i - 4) * (2 * i - 4)) * DSC
                                  : -1e38f;
            const f2 dxt = (f2){dxa, dxb};
#pragma unroll
            for (int c = 0; c < T; ++c) {
                const f2 d = v - ci[c];
                f2 t = d * KI;
                t = __builtin_elementwise_fma(t, d, dxt);
                const float w0 = __builtin_amdgcn_exp2f(t.x) * dyw[c];
                const float w1 = __builtin_amdgcn_exp2f(t.y) * dyw[c];
                den[c] += (f2){w0, w1};
                num[c] = __builtin_elementwise_fma(splat4(w0), p0, num[c]);
                num[c] = __builtin_elementwise_fma(splat4(w1), p1, num[c]);
            }
        }
    }

    // Fold the T centers' contributions: sum_c p_f(c) * {num,den}(c)
    f4 numv = splat4(0.f);
    f4 denv = splat4(0.f);
#pragma unroll
    for (int c = 0; c < T; ++c) {
        const f4 pc = slab[(r0 + c + RAD) * SSTR + tx + RAD];
        numv = __builtin_elementwise_fma(pc, num[c], numv);
        denv = __builtin_elementwise_fma(pc, splat4(den[c].x + den[c].y), denv);
    }

    float vals[8] = {numv.x, numv.y, numv.z, numv.w, denv.x, denv.y, denv.z, denv.w};

#pragma unroll
    for (int i = 0; i < 8; ++i) {
        float v = vals[i];
#pragma unroll
        for (int off = 32; off > 0; off >>= 1) v += __shfl_down(v, off, 64);
        vals[i] = v;
    }

    const int wave = tid >> 6, lane = tid & 63;
    if (lane == 0) {
#pragma unroll
        for (int i = 0; i < 8; ++i) red[wave][i] = vals[i];
    }
    __syncthreads();

    if (tid < 8) {
        const int gid = blockIdx.x + GXD * blockIdx.y + GXD * GYD * blockIdx.z;
        acc[gid * 8 + tid] = red[0][tid] + red[1][tid];
    }
}

__global__ void ncut_final(const float* __restrict__ acc, float* __restrict__ out) {
    const int t = threadIdx.x;          // 64
    const int k = t & 3, b = (t >> 2) & 7, part = t >> 5;
    float s = 0.f;
    for (int j = 0; j < PB; ++j) s += acc[(b * PB + j) * 8 + k + 4 * part];
    const float den = __shfl(s, (t + 32) & 63, 64);
    float r = (t < 32) ? fabsf(s / den) : 0.f;
#pragma unroll
    for (int off = 32; off > 0; off >>= 1) r += __shfl_down(r, off, 64);
    if (t == 0) out[0] = (float)Kc - r * (1.0f / (float)Bb);
}

extern "C" void kernel_launch(void* const* d_in, const int* in_sizes, int n_in,
                              void* d_out, int out_size, void* d_ws, size_t ws_size,
                              hipStream_t stream) {
    const float* images = (const float*)d_in[0];
    const float* labels = (const float*)d_in[1];
    float* out = (float*)d_out;
    float* acc = (float*)d_ws;  // PB*Bb blocks * 8 partials, fully overwritten each launch

    dim3 grid(GXD, GYD, Bb);    // 7 x 14 x 8
    ncut_main<<<grid, 128, 0, stream>>>(images, labels, acc);
    ncut_final<<<1, 64, 0, stream>>>(acc, out);
}